// Round 11
// baseline (123.051 us; speedup 1.0000x reference)
//
#include <hip/hip_runtime.h>
#include <stdint.h>

typedef float    f32x4  __attribute__((ext_vector_type(4)));
typedef __bf16   bf16x8 __attribute__((ext_vector_type(8)));
typedef short    s16x8  __attribute__((ext_vector_type(8)));
typedef int      i32x4  __attribute__((ext_vector_type(4)));
typedef unsigned short u16x4 __attribute__((ext_vector_type(4)));

#define DEVINL __device__ __forceinline__

DEVINL unsigned short f2bf(float f) {
  unsigned u = __builtin_bit_cast(unsigned, f);
  return (unsigned short)((u + 0x7fffu + ((u >> 16) & 1u)) >> 16);
}

DEVINL f32x4 mfma16(bf16x8 a, bf16x8 b, f32x4 c) {
  return __builtin_amdgcn_mfma_f32_16x16x32_bf16(a, b, c, 0, 0, 0);
}

DEVINL bf16x8 lds_frag(const unsigned char* p) {
  return __builtin_bit_cast(bf16x8, *(const s16x8*)p);
}

template <int CTRL>
DEVINL float dppf(float x) {
  int xi = __builtin_bit_cast(int, x);
  return __builtin_bit_cast(float, __builtin_amdgcn_update_dpp(xi, xi, CTRL, 0xF, 0xF, true));
}
DEVINL float redmax16(float v) {
  v = fmaxf(v, dppf<0xB1>(v));
  v = fmaxf(v, dppf<0x4E>(v));
  v = fmaxf(v, dppf<0x141>(v));
  v = fmaxf(v, dppf<0x140>(v));
  return v;
}

// ---------------- prep: convert the 4 weight matrices to bf16 ----------------
__global__ __launch_bounds__(256) void prep_w_kernel(
    const float* __restrict__ wq, const float* __restrict__ wk,
    const float* __restrict__ wv, const float* __restrict__ wp,
    unsigned short* __restrict__ wbf) {
  int id = blockIdx.x * 256 + threadIdx.x;
  int m = id >> 12;
  const float* src = (m == 0) ? wq : (m == 1) ? wk : (m == 2) ? wv : wp;
  f32x4 v = ((const f32x4*)src)[id & 4095];
  u16x4 o;
  o[0] = f2bf(v[0]); o[1] = f2bf(v[1]); o[2] = f2bf(v[2]); o[3] = f2bf(v[3]);
  ((u16x4*)wbf)[id] = o;
}

// ---------------- QKV, split 3-way: grid 384 = {Q,K,V} x 128 s-tiles --------
__global__ __launch_bounds__(256) void qkv_kernel(
    const float* __restrict__ x, const float* __restrict__ wav,
    const unsigned short* __restrict__ wbf,
    const float* __restrict__ bq, const float* __restrict__ bk, const float* __restrict__ bv,
    unsigned short* __restrict__ Qb, unsigned short* __restrict__ Kb,
    unsigned short* __restrict__ Vt) {
  __shared__ __align__(16) unsigned char sm[32768];
  const int tid = threadIdx.x;
  const int g = blockIdx.x >> 7;
  const int s0 = (blockIdx.x & 127) * 64;
  const float* srcm = (g == 0) ? x : wav;

  {
    const int c = tid >> 1, half = tid & 1;
    const float* xs = srcm + c * 8192 + s0 + half * 32;
#pragma unroll
    for (int i = 0; i < 8; ++i) {
      f32x4 vx = *(const f32x4*)(xs + i * 4);
#pragma unroll
      for (int j = 0; j < 4; ++j) {
        int s = half * 32 + i * 4 + j;
        int off = (c * 2) ^ ((s & 7) << 4);
        *(unsigned short*)(sm + s * 256 + off) = f2bf(vx[j]);
      }
    }
  }
  __syncthreads();

  const int w = tid >> 6, l = tid & 63, lr = l & 15, lh = l >> 4;
  const int arow = w * 16 + lr;
  const int aswz = (lr & 7) << 4;

  const unsigned char* asrc = sm + arow * 256;
  const unsigned char* wsrc = (const unsigned char*)wbf + g * 32768;
  f32x4 acc[8];
#pragma unroll
  for (int jt = 0; jt < 8; ++jt) acc[jt] = (f32x4){0.f, 0.f, 0.f, 0.f};
#pragma unroll
  for (int ks = 0; ks < 4; ++ks) {
    bf16x8 a = lds_frag(asrc + ((ks * 64 + lh * 16) ^ aswz));
#pragma unroll
    for (int jt = 0; jt < 8; ++jt) {
      bf16x8 bb = __builtin_bit_cast(
          bf16x8, *(const s16x8*)(wsrc + (jt * 16 + lr) * 256 + ks * 64 + lh * 16));
      acc[jt] = mfma16(a, bb, acc[jt]);
    }
  }
  if (g < 2) {
    const float* bias = g ? bk : bq;
    unsigned short* outp = g ? Kb : Qb;
#pragma unroll
    for (int jt = 0; jt < 8; ++jt) {
      float bb = bias[jt * 16 + lr];
#pragma unroll
      for (int r = 0; r < 4; ++r) {
        int row = s0 + w * 16 + lh * 4 + r;
        outp[row * 128 + jt * 16 + lr] = f2bf(acc[jt][r] + bb);
      }
    }
  } else {
    unsigned char* sm2 = sm + 16384;
#pragma unroll
    for (int jt = 0; jt < 8; ++jt) {
      float bb = bv[jt * 16 + lr];
#pragma unroll
      for (int r = 0; r < 4; ++r) {
        int jj = jt * 16 + lr;
        int sl = w * 16 + lh * 4 + r;
        *(unsigned short*)(sm2 + jj * 128 + ((sl * 2) ^ ((jj & 7) << 4))) =
            f2bf(acc[jt][r] + bb);
      }
    }
    __syncthreads();
#pragma unroll
    for (int g2 = 0; g2 < 4; ++g2) {
      int jj = w * 32 + g2 * 8 + (l >> 3);
      s16x8 row = *(const s16x8*)(sm2 + jj * 128 + (((l & 7) * 16) ^ ((jj & 7) << 4)));
      *(s16x8*)(Vt + jj * 8192 + s0 + (l & 7) * 8) = row;
    }
  }
}

// ---------------- flash attention: QBLK=128 (2 q-groups), KVBLK=64, split-KV --
// grid = 128*S; bid: sp = bid>>7, g = bid&127, h = g&1, qb2 = g>>1 (q0 = qb2*128).
// Each wave: 16 q of group A (q0..q0+63) and 16 q of group B (q0+64..q0+127).
// Every K/V LDS frag read feeds 2 MFMAs -> ~half the LDS bytes per FLOP.
// LDS: K @0 (8KB), V @8192, P_A @16384, P_B @24576 = 32KB. All rows 128B,
// XOR ((row&7)<<4) — the measured-zero-conflict form. 2-barrier loop (R7).
__global__ __launch_bounds__(256) void attn_kernel(
    const unsigned short* __restrict__ Qb, const unsigned short* __restrict__ Kb,
    const unsigned short* __restrict__ Vt, float* __restrict__ Opart,
    float* __restrict__ Ml, float* __restrict__ Ll, int NIT) {
  __shared__ __align__(16) unsigned char sm[32768];
  const int tid = threadIdx.x;
  const int bid = blockIdx.x;
  const int sp = bid >> 7, g = bid & 127;
  const int h = g & 1, qb2 = g >> 1;
  const int q0 = qb2 * 128;
  const int t0 = sp * NIT;  // in 64-key tiles
  const int w = tid >> 6, l = tid & 63, lr = l & 15, lh = l >> 4;
  const int lswz = (lr & 7) << 4;

  bf16x8 qfA[2], qfB[2];
#pragma unroll
  for (int ks = 0; ks < 2; ++ks) {
    qfA[ks] = __builtin_bit_cast(
        bf16x8, *(const s16x8*)(Qb + (q0 + w * 16 + lr) * 128 + h * 64 + ks * 32 + lh * 8));
    qfB[ks] = __builtin_bit_cast(
        bf16x8, *(const s16x8*)(Qb + (q0 + 64 + w * 16 + lr) * 128 + h * 64 + ks * 32 + lh * 8));
  }

  const s16x8 ones_i = {0x3F80, 0x3F80, 0x3F80, 0x3F80, 0x3F80, 0x3F80, 0x3F80, 0x3F80};
  const bf16x8 onesf = __builtin_bit_cast(bf16x8, ones_i);

  f32x4 accA[4], accB[4];
  float mA[4], lA[4], mB[4], lB[4];
#pragma unroll
  for (int i = 0; i < 4; ++i) {
    accA[i] = (f32x4){0.f,0.f,0.f,0.f}; accB[i] = (f32x4){0.f,0.f,0.f,0.f};
    mA[i] = -1e30f; lA[i] = 0.f; mB[i] = -1e30f; lB[i] = 0.f;
  }

  // staging geometry (verbatim R7): 512 chunks of 16B each for K and V
  int srow[2], soff[2], sldsoff[2];
#pragma unroll
  for (int i = 0; i < 2; ++i) {
    int ch = tid + i * 256;
    srow[i] = ch >> 3;
    soff[i] = (ch & 7) * 8;
    sldsoff[i] = srow[i] * 128 + ((soff[i] * 2) ^ ((srow[i] & 7) << 4));
  }

  {  // prologue: stage tile t0
#pragma unroll
    for (int i = 0; i < 2; ++i) {
      i32x4 kv = *(const i32x4*)(Kb + (t0 * 64 + srow[i]) * 128 + h * 64 + soff[i]);
      i32x4 vv = *(const i32x4*)(Vt + (h * 64 + srow[i]) * 8192 + t0 * 64 + soff[i]);
      *(i32x4*)(sm + sldsoff[i]) = kv;
      *(i32x4*)(sm + 8192 + sldsoff[i]) = vv;
    }
  }
  __syncthreads();

  const float sc = 0.18033688011112042f;  // 1/sqrt(64) * log2(e)

  for (int tt = 0; tt < NIT; ++tt) {
    const int t = t0 + tt;
    i32x4 nk[2], nv[2];
    if (tt < NIT - 1) {  // register prefetch of next tile
#pragma unroll
      for (int i = 0; i < 2; ++i) {
        nk[i] = *(const i32x4*)(Kb + ((t + 1) * 64 + srow[i]) * 128 + h * 64 + soff[i]);
        nv[i] = *(const i32x4*)(Vt + (h * 64 + srow[i]) * 8192 + (t + 1) * 64 + soff[i]);
      }
    }
    const unsigned char* kb = sm;
    const unsigned char* vb = sm + 8192;
    unsigned char* pbA = sm + 16384;
    unsigned char* pbB = sm + 24576;

    // QK^T: each kf read feeds BOTH q-groups
    f32x4 sA[4], sB[4];
#pragma unroll
    for (int nt = 0; nt < 4; ++nt) { sA[nt] = (f32x4){0.f,0.f,0.f,0.f}; sB[nt] = (f32x4){0.f,0.f,0.f,0.f}; }
#pragma unroll
    for (int ks = 0; ks < 2; ++ks) {
#pragma unroll
      for (int nt = 0; nt < 4; ++nt) {
        bf16x8 kf = lds_frag(kb + (nt * 16 + lr) * 128 + ((ks * 64 + lh * 16) ^ lswz));
        sA[nt] = mfma16(qfA[ks], kf, sA[nt]);
        sB[nt] = mfma16(qfB[ks], kf, sB[nt]);
      }
    }

    // online softmax per group (single pass; l via ones-MFMA below)
#pragma unroll
    for (int r = 0; r < 4; ++r) {
      float mx = fmaxf(fmaxf(sA[0][r], sA[1][r]), fmaxf(sA[2][r], sA[3][r]));
      mx = redmax16(mx) * sc;
      float mn = fmaxf(mA[r], mx);
      float al = __builtin_amdgcn_exp2f(mA[r] - mn);
      mA[r] = mn;
      lA[r] *= al;
#pragma unroll
      for (int nt = 0; nt < 4; ++nt)
        sA[nt][r] = __builtin_amdgcn_exp2f(fmaf(sA[nt][r], sc, -mn));
#pragma unroll
      for (int ct = 0; ct < 4; ++ct) accA[ct][r] *= al;
    }
#pragma unroll
    for (int r = 0; r < 4; ++r) {
      float mx = fmaxf(fmaxf(sB[0][r], sB[1][r]), fmaxf(sB[2][r], sB[3][r]));
      mx = redmax16(mx) * sc;
      float mn = fmaxf(mB[r], mx);
      float al = __builtin_amdgcn_exp2f(mB[r] - mn);
      mB[r] = mn;
      lB[r] *= al;
#pragma unroll
      for (int nt = 0; nt < 4; ++nt)
        sB[nt][r] = __builtin_amdgcn_exp2f(fmaf(sB[nt][r], sc, -mn));
#pragma unroll
      for (int ct = 0; ct < 4; ++ct) accB[ct][r] *= al;
    }

    // P -> bf16 -> per-group LDS regions (R7 pattern, per-wave-private rows)
    const int qrow = w * 16 + lh * 4;
#pragma unroll
    for (int r = 0; r < 4; r += 2) {
      int qa = qrow + r, qb = qrow + r + 1;
      int swza = (qa & 7) << 4, swzb = (qb & 7) << 4;
#pragma unroll
      for (int nt = 0; nt < 4; ++nt) {
        int koff = (nt * 16 + lr) * 2;
        unsigned u;
        asm("v_cvt_pk_bf16_f32 %0, %1, %2" : "=v"(u) : "v"(sA[nt][r]), "v"(sA[nt][r + 1]));
        *(unsigned short*)(pbA + qa * 128 + (koff ^ swza)) = (unsigned short)u;
        *(unsigned short*)(pbA + qb * 128 + (koff ^ swzb)) = (unsigned short)(u >> 16);
        asm("v_cvt_pk_bf16_f32 %0, %1, %2" : "=v"(u) : "v"(sB[nt][r]), "v"(sB[nt][r + 1]));
        *(unsigned short*)(pbB + qa * 128 + (koff ^ swza)) = (unsigned short)u;
        *(unsigned short*)(pbB + qb * 128 + (koff ^ swzb)) = (unsigned short)(u >> 16);
      }
    }
    asm volatile("s_waitcnt lgkmcnt(0)" ::: "memory");
    __builtin_amdgcn_sched_barrier(0);

    // PV: each vf read feeds BOTH groups; l via ones-MFMA
    bf16x8 paA[2], paB[2];
#pragma unroll
    for (int ks = 0; ks < 2; ++ks) {
      paA[ks] = lds_frag(pbA + (w * 16 + lr) * 128 + ((ks * 64 + lh * 16) ^ lswz));
      paB[ks] = lds_frag(pbB + (w * 16 + lr) * 128 + ((ks * 64 + lh * 16) ^ lswz));
    }
    f32x4 ltA = (f32x4){0.f,0.f,0.f,0.f}, ltB = (f32x4){0.f,0.f,0.f,0.f};
#pragma unroll
    for (int ks = 0; ks < 2; ++ks) {
      ltA = mfma16(paA[ks], onesf, ltA);
      ltB = mfma16(paB[ks], onesf, ltB);
#pragma unroll
      for (int ct = 0; ct < 4; ++ct) {
        bf16x8 vf = lds_frag(vb + (ct * 16 + lr) * 128 + ((ks * 64 + lh * 16) ^ lswz));
        accA[ct] = mfma16(paA[ks], vf, accA[ct]);
        accB[ct] = mfma16(paB[ks], vf, accB[ct]);
      }
    }
#pragma unroll
    for (int r = 0; r < 4; ++r) { lA[r] += ltA[r]; lB[r] += ltB[r]; }

    __syncthreads();
    if (tt < NIT - 1) {
#pragma unroll
      for (int i = 0; i < 2; ++i) {
        *(i32x4*)(sm + sldsoff[i]) = nk[i];
        *(i32x4*)(sm + 8192 + sldsoff[i]) = nv[i];
      }
    }
    __syncthreads();
  }

  // epilogue: write both groups to the R7-compatible partial slots
  // group A covers q-tile 2*qb2 -> hq = 4*qb2 + h; group B -> hq = 4*qb2 + 2 + h
  const size_t pbA_i = (size_t)sp * 256 + 4 * qb2 + h;
  const size_t pbB_i = (size_t)sp * 256 + 4 * qb2 + 2 + h;
  float* opA = Opart + pbA_i * 4096;
  float* opB = Opart + pbB_i * 4096;
#pragma unroll
  for (int ct = 0; ct < 4; ++ct) {
#pragma unroll
    for (int r = 0; r < 4; ++r) {
      int q = w * 16 + lh * 4 + r;
      opA[q * 64 + ct * 16 + lr] = accA[ct][r];
      opB[q * 64 + ct * 16 + lr] = accB[ct][r];
    }
  }
  if (lr == 0) {
#pragma unroll
    for (int r = 0; r < 4; ++r) {
      int q = w * 16 + lh * 4 + r;
      Ml[pbA_i * 64 + q] = mA[r];
      Ll[pbA_i * 64 + q] = lA[r];
      Ml[pbB_i * 64 + q] = mB[r];
      Ll[pbB_i * 64 + q] = lB[r];
    }
  }
}

// ---------------- combine v3: coalesced merge of S partials ------------------
__global__ __launch_bounds__(256) void combine_kernel(
    const float* __restrict__ Opart, const float* __restrict__ Ml,
    const float* __restrict__ Ll, unsigned short* __restrict__ Ot, int S) {
  __shared__ float wgt_s[8][32];
  __shared__ float rinv_s[32];
  __shared__ unsigned short lt[64][34];
  const int bid = blockIdx.x;
  const int hq = bid >> 1, half = bid & 1;
  const int h = hq & 1, q0 = (hq >> 1) * 64;
  const int t = threadIdx.x;

  if (t < 32) {
    int qg = half * 32 + t;
    float m8[8];
    float M = -1e30f;
    for (int sp = 0; sp < S; ++sp) {
      m8[sp] = Ml[(size_t)(sp * 256 + hq) * 64 + qg];
      M = fmaxf(M, m8[sp]);
    }
    float L = 0.f;
    for (int sp = 0; sp < S; ++sp) {
      float wv = __builtin_amdgcn_exp2f(m8[sp] - M);
      wgt_s[sp][t] = wv;
      L += Ll[(size_t)(sp * 256 + hq) * 64 + qg] * wv;
    }
    rinv_s[t] = 1.0f / L;
  }
  __syncthreads();

  const int q = t >> 3;
  const int dc = t & 7;
  const int qg = half * 32 + q;
  f32x4 o0 = (f32x4){0.f,0.f,0.f,0.f}, o1 = (f32x4){0.f,0.f,0.f,0.f};
  for (int sp = 0; sp < S; ++sp) {
    const f32x4* src =
        (const f32x4*)(Opart + (size_t)(sp * 256 + hq) * 4096 + qg * 64 + dc * 8);
    float wv = wgt_s[sp][q];
    o0 += src[0] * wv;
    o1 += src[1] * wv;
  }
  float rinv = rinv_s[q];
#pragma unroll
  for (int j = 0; j < 4; ++j) lt[dc * 8 + j][q] = f2bf(o0[j] * rinv);
#pragma unroll
  for (int j = 0; j < 4; ++j) lt[dc * 8 + 4 + j][q] = f2bf(o1[j] * rinv);
  __syncthreads();

  const int d = t >> 2, q8 = (t & 3) * 8;
  unsigned short tmp[8];
#pragma unroll
  for (int j = 0; j < 8; ++j) tmp[j] = lt[d][q8 + j];
  *(s16x8*)(Ot + (size_t)(h * 64 + d) * 8192 + q0 + half * 32 + q8) = *(s16x8*)tmp;
}

// ---------------- proj: out[(c,hp)][wq] = Ot[(c,hp)][wp] Wp^T + bp (f32 out) ---
__global__ __launch_bounds__(256) void proj_kernel(
    const unsigned short* __restrict__ Ot, const unsigned short* __restrict__ wbf,
    const float* __restrict__ bp, float* __restrict__ out) {
  __shared__ __align__(16) unsigned char sm[16384];
  const int tid = threadIdx.x;
  const int r0 = blockIdx.x * 64;
#pragma unroll
  for (int i = 0; i < 4; ++i) {
    int chk = tid + 256 * i;
    i32x4 v = *(const i32x4*)(Ot + r0 * 128 + chk * 8);
    int row = chk >> 4, off = (chk & 15) * 16;
    *(i32x4*)(sm + row * 256 + (off ^ ((row & 7) << 4))) = v;
  }
  __syncthreads();
  const int w = tid >> 6, l = tid & 63, lr = l & 15, lh = l >> 4;
  f32x4 acc[8];
#pragma unroll
  for (int jt = 0; jt < 8; ++jt) acc[jt] = (f32x4){0.f, 0.f, 0.f, 0.f};
  const unsigned char* wsrc = (const unsigned char*)wbf + 3 * 32768;
#pragma unroll
  for (int ks = 0; ks < 4; ++ks) {
    bf16x8 a = lds_frag(sm + (w * 16 + lr) * 256 + ((ks * 64 + lh * 16) ^ ((lr & 7) << 4)));
#pragma unroll
    for (int jt = 0; jt < 8; ++jt) {
      bf16x8 bb = __builtin_bit_cast(
          bf16x8, *(const s16x8*)(wsrc + (jt * 16 + lr) * 256 + ks * 64 + lh * 16));
      acc[jt] = mfma16(a, bb, acc[jt]);
    }
  }
#pragma unroll
  for (int jt = 0; jt < 8; ++jt) {
    float bb = bp[jt * 16 + lr];
#pragma unroll
    for (int r = 0; r < 4; ++r)
      out[(r0 + w * 16 + lh * 4 + r) * 128 + jt * 16 + lr] = acc[jt][r] + bb;
  }
}

extern "C" void kernel_launch(void* const* d_in, const int* in_sizes, int n_in,
                              void* d_out, int out_size, void* d_ws, size_t ws_size,
                              hipStream_t stream) {
  const float* x   = (const float*)d_in[0];
  const float* wav = (const float*)d_in[1];
  const float* Wq  = (const float*)d_in[2];
  const float* bq  = (const float*)d_in[3];
  const float* Wk  = (const float*)d_in[4];
  const float* bk  = (const float*)d_in[5];
  const float* Wv  = (const float*)d_in[6];
  const float* bv  = (const float*)d_in[7];
  const float* Wp  = (const float*)d_in[8];
  const float* bp  = (const float*)d_in[9];
  (void)in_sizes; (void)n_in; (void)out_size;

  unsigned char* ws = (unsigned char*)d_ws;
  unsigned short* Qb  = (unsigned short*)(ws);                 // [8192][128] bf16, 2MB
  unsigned short* Kb  = (unsigned short*)(ws + 2097152);       // [8192][128]
  unsigned short* Vt  = (unsigned short*)(ws + 4194304);       // [128][8192]
  unsigned short* Ot  = (unsigned short*)(ws + 6291456);       // [128][8192]
  unsigned short* Wbf = (unsigned short*)(ws + 8388608);       // 4x[128][128] bf16 (128KB)

  // split-KV factor from workspace budget: per-S bytes = 4MB Opart + 128KB m/l
  const size_t pbase = 8519680;
  int S = 8;
  while (S > 1 && pbase + (size_t)S * 4325376 > ws_size) S >>= 1;
  float* Opart = (float*)(ws + pbase);
  float* Ml    = (float*)(ws + pbase + (size_t)S * 4194304);
  float* Ll    = (float*)(ws + pbase + (size_t)S * 4194304 + (size_t)S * 65536);
  const int NIT = 128 / S;  // 64-key tiles per block

  prep_w_kernel<<<64, 256, 0, stream>>>(Wq, Wk, Wv, Wp, Wbf);
  qkv_kernel<<<384, 256, 0, stream>>>(x, wav, Wbf, bq, bk, bv, Qb, Kb, Vt);
  attn_kernel<<<128 * S, 256, 0, stream>>>(Qb, Kb, Vt, Opart, Ml, Ll, NIT);
  combine_kernel<<<512, 256, 0, stream>>>(Opart, Ml, Ll, Ot, S);
  proj_kernel<<<128, 256, 0, stream>>>(Ot, Wbf, bp, (float*)d_out);
}